// Round 8
// baseline (726.304 us; speedup 1.0000x reference)
//
#include <hip/hip_runtime.h>

#define N_NODES  131072
#define N_GRAPHS 4096
#define HID      512
#define CHUNK_G  1024
#define N_CHUNKS 4
#define B_BLOCKS 516

typedef float  f32x4  __attribute__((ext_vector_type(4)));
typedef __bf16 bf16x8 __attribute__((ext_vector_type(8)));
typedef unsigned short u16x8 __attribute__((ext_vector_type(8)));

__device__ __forceinline__ unsigned short f2bf(float f) {
  unsigned int u = __builtin_bit_cast(unsigned int, f);
  u += 0x7FFFu + ((u >> 16) & 1u);   // round-to-nearest-even
  return (unsigned short)(u >> 16);
}
__device__ __forceinline__ f32x4 mfma_bf16(bf16x8 a, bf16x8 b, f32x4 c) {
  return __builtin_amdgcn_mfma_f32_16x16x32_bf16(a, b, c, 0, 0, 0);
}

// ---------- bucket: per-chunk sort of graphs by branch ----------
__global__ __launch_bounds__(512) void bucket_kernel(
    const int* __restrict__ dsid, int* __restrict__ perm, int* __restrict__ meta) {
  __shared__ int cnt[N_CHUNKS][4], base[N_CHUNKS][4], off[N_CHUNKS][4];
  int t = threadIdx.x;
  if (t < N_CHUNKS * 4) { (&cnt[0][0])[t] = 0; (&off[0][0])[t] = 0; }
  __syncthreads();
  for (int g = t; g < N_GRAPHS; g += 512) atomicAdd(&cnt[g / CHUNK_G][dsid[g]], 1);
  __syncthreads();
  if (t < N_CHUNKS) {
    int s = 0;
    for (int b = 0; b < 4; ++b) { base[t][b] = s; s += cnt[t][b]; meta[t * 4 + b] = cnt[t][b]; }
  }
  __syncthreads();
  for (int g = t; g < N_GRAPHS; g += 512) {
    int c = g / CHUNK_G, b = dsid[g];
    perm[c * CHUNK_G + base[c][b] + atomicAdd(&off[c][b], 1)] = g;
  }
}

// ---------- prep: W[b][k][n] fp32 -> fragment-ordered bf16 -------------------
// [b][hf=32][kk=16][lane=64][e=8]; value = W[k=kk*32+(lane>>4)*8+e][n=hf*16+(lane&15)]
__global__ __launch_bounds__(256) void prep_wf_kernel(
    const float* __restrict__ Wn1, const float* __restrict__ Ws,
    unsigned short* __restrict__ W1Tf, unsigned short* __restrict__ WsTf) {
  __shared__ unsigned short lt[8192];
  const int bid = blockIdx.x;          // 256 blocks
  const int which = bid >> 7;
  const int b  = (bid >> 5) & 3;
  const int hf = bid & 31;
  const float* src = (which ? Ws : Wn1) + (size_t)b * 512 * 512 + hf * 16;
  unsigned short* dst = (which ? WsTf : W1Tf) + (size_t)(b * 32 + hf) * 8192;
  const int t = threadIdx.x;
  for (int i = t; i < 8192; i += 256) {
    int k = i >> 4;
    int n = i & 15;
    float v = src[(size_t)k * 512 + n];
    int kk = k >> 5, lane = n + ((k >> 3) & 3) * 16, e = k & 7;
    lt[(kk * 64 + lane) * 8 + e] = f2bf(v);
  }
  __syncthreads();
  u16x8* d8 = (u16x8*)dst;
  const u16x8* s8 = (const u16x8*)lt;
  for (int i = t; i < 1024; i += 256) d8[i] = s8[i];
}

// ---------- prep: Wg (4,512,100) -> WgT [b][128][512] bf16 zero-pad ----------
__global__ __launch_bounds__(256) void prep_wg_kernel(
    const float* __restrict__ Wg, unsigned short* __restrict__ WgT) {
  int idx = blockIdx.x * 256 + threadIdx.x;   // 1024 blocks
  int b = idx >> 16;
  int r = (idx >> 9) & 127;
  int k = idx & 511;
  float v = (r < 100) ? Wg[(b * 512 + k) * 100 + r] : 0.f;
  WgT[idx] = f2bf(v);
}

// ---------- A: convert x fp32 -> fragment-ordered bf16 + graph mean ----------
// 1 block = 1 graph, 512 thr, no LDS, tiny regs -> max occupancy streaming.
// Wave w, iter i: task (nf=i>>1, kk=w*2+(i&1)); lane reads x[nf*16+l15][kk*32+l4*8..+8],
// stores 16B wave-linear into xb[g][((nf*16+kk)*64+lane)*8]. Pool via shfl over l15.
__global__ __launch_bounds__(512) void convert_pool_kernel(
    const float* __restrict__ x,
    unsigned short* __restrict__ xb,     // chunk buffer [CHUNK_G][16384]
    unsigned short* __restrict__ xg,     // full [4096][512]
    int gbase) {
  const int gl = blockIdx.x;
  const int g  = gbase + gl;
  const int t = threadIdx.x;
  const int lane = t & 63, w = t >> 6, l15 = lane & 15, l4 = lane >> 4;
  const float* xs = x + (size_t)g * 32 * HID;
  unsigned short* xd = xb + (size_t)gl * 16384;
  float ps[2][8];
  #pragma unroll
  for (int j = 0; j < 2; ++j)
    #pragma unroll
    for (int e = 0; e < 8; ++e) ps[j][e] = 0.f;
  #pragma unroll
  for (int i = 0; i < 4; ++i) {
    const int kk = w * 2 + (i & 1), nf = i >> 1, pi = i & 1;
    const int row = nf * 16 + l15, col = kk * 32 + l4 * 8;
    float4 p0 = *(const float4*)(xs + (size_t)row * HID + col);
    float4 p1 = *(const float4*)(xs + (size_t)row * HID + col + 4);
    u16x8 ua;
    ua[0]=f2bf(p0.x); ua[1]=f2bf(p0.y); ua[2]=f2bf(p0.z); ua[3]=f2bf(p0.w);
    ua[4]=f2bf(p1.x); ua[5]=f2bf(p1.y); ua[6]=f2bf(p1.z); ua[7]=f2bf(p1.w);
    *(u16x8*)&xd[((nf * 16 + kk) * 64 + lane) * 8] = ua;
    ps[pi][0]+=p0.x; ps[pi][1]+=p0.y; ps[pi][2]+=p0.z; ps[pi][3]+=p0.w;
    ps[pi][4]+=p1.x; ps[pi][5]+=p1.y; ps[pi][6]+=p1.z; ps[pi][7]+=p1.w;
  }
  #pragma unroll
  for (int j = 0; j < 2; ++j)
    #pragma unroll
    for (int e = 0; e < 8; ++e) {
      ps[j][e] += __shfl_xor(ps[j][e], 1);
      ps[j][e] += __shfl_xor(ps[j][e], 2);
      ps[j][e] += __shfl_xor(ps[j][e], 4);
      ps[j][e] += __shfl_xor(ps[j][e], 8);
    }
  if (l15 == 0) {
    #pragma unroll
    for (int j = 0; j < 2; ++j) {
      int kk = w * 2 + j;
      u16x8 o;
      #pragma unroll
      for (int e = 0; e < 8; ++e) o[e] = f2bf(ps[j][e] * (1.f / 32.f));
      *(u16x8*)&xg[(size_t)g * HID + kk * 32 + l4 * 8] = o;
    }
  }
}

// ---------- B: node GEMM, M=64 (2 same-branch graphs), 512 thr / 8 waves -----
// LDS: 64KB bf16 copy of 2 graph tiles (lane-linear, conflict-free) + 12KB red.
// 2 slices x (wave owns 2 hf): acc[2][4]=32 AGPR, ~90 unified regs -> runahead room.
// Barrier-free K=512 loop; fused stage-2; 2 blocks/CU.
__global__ __launch_bounds__(512, 4) void node_gemm_kernel(
    const unsigned short* __restrict__ xb,
    const int* __restrict__ metac,       // this chunk's 4 counts
    const int* __restrict__ permc,       // this chunk's CHUNK_G perm
    const unsigned short* __restrict__ W1Tf,
    const float* __restrict__ bn1,
    const float* __restrict__ Wn2,
    const float* __restrict__ bn2,
    float* __restrict__ n_head,
    float* __restrict__ n_var,
    int gbase) {
  __shared__ __align__(16) unsigned short xtile[32768];  // 64 KB
  __shared__ __align__(16) float red[8][64][6];          // 12 KB

  const int4 cvv = *(const int4*)metac;
  const int cnts[4] = {cvv.x, cvv.y, cvv.z, cvv.w};
  int i = blockIdx.x, branch = -1, permOff = 0, nvalid = 0, pb = 0;
  for (int b = 0; b < 4; ++b) {
    int nt = (cnts[b] + 1) >> 1;
    if (branch < 0 && i < nt) { branch = b; permOff = pb + i * 2; nvalid = min(2, cnts[b] - i * 2); }
    if (branch < 0) i -= nt;
    pb += cnts[b];
  }
  if (branch < 0) return;

  const int t = threadIdx.x;
  const int lane = t & 63, w = t >> 6, l15 = lane & 15, l4 = lane >> 4;
  const int g0 = permc[permOff];
  const int g1 = permc[permOff + (nvalid > 1 ? 1 : 0)];

  // LDS fill: plain bf16 copy, already fragment-ordered
  const unsigned short* s0 = xb + (size_t)(g0 - gbase) * 16384;
  const unsigned short* s1 = xb + (size_t)(g1 - gbase) * 16384;
  #pragma unroll
  for (int ii = 0; ii < 4; ++ii) {
    int idx = (t + ii * 512) * 8;
    *(u16x8*)&xtile[idx]         = *(const u16x8*)&s0[idx];
    *(u16x8*)&xtile[16384 + idx] = *(const u16x8*)&s1[idx];
  }
  __syncthreads();

  float part[4][6];
  #pragma unroll
  for (int n = 0; n < 4; ++n)
    #pragma unroll
    for (int j = 0; j < 6; ++j) part[n][j] = 0.f;
  const float* B1 = bn1 + branch * HID;
  const float* W2 = Wn2 + branch * HID * 6;

  #pragma unroll
  for (int s = 0; s < 2; ++s) {
    const unsigned short* wb =
        W1Tf + ((size_t)(branch * 32 + s * 16 + w * 2)) * 8192 + lane * 8;
    f32x4 acc[2][4];
    #pragma unroll
    for (int m = 0; m < 2; ++m)
      #pragma unroll
      for (int n = 0; n < 4; ++n) acc[m][n] = (f32x4)0.f;

    #pragma unroll
    for (int kk = 0; kk < 16; ++kk) {
      bf16x8 af0 = *(const bf16x8*)(wb + kk * 512);
      bf16x8 af1 = *(const bf16x8*)(wb + 8192 + kk * 512);
      bf16x8 bfr[4];
      #pragma unroll
      for (int n = 0; n < 4; ++n)
        bfr[n] = *(const bf16x8*)&xtile[(n * 16 + kk) * 512 + lane * 8];
      #pragma unroll
      for (int n = 0; n < 4; ++n) {
        acc[0][n] = mfma_bf16(af0, bfr[n], acc[0][n]);
        acc[1][n] = mfma_bf16(af1, bfr[n], acc[1][n]);
      }
    }
    // fused stage-2 partial over this slice's 32 hcols per lane
    #pragma unroll
    for (int m = 0; m < 2; ++m) {
      #pragma unroll
      for (int r = 0; r < 4; ++r) {
        int hcol = (s * 16 + w * 2 + m) * 16 + l4 * 4 + r;
        float b1 = B1[hcol];
        float w2[6];
        #pragma unroll
        for (int j = 0; j < 6; ++j) w2[j] = W2[hcol * 6 + j];
        #pragma unroll
        for (int n = 0; n < 4; ++n) {
          float h = fmaxf(acc[m][n][r] + b1, 0.f);
          #pragma unroll
          for (int j = 0; j < 6; ++j) part[n][j] += h * w2[j];
        }
      }
    }
  }

  #pragma unroll
  for (int n = 0; n < 4; ++n)
    #pragma unroll
    for (int j = 0; j < 6; ++j) {
      part[n][j] += __shfl_xor(part[n][j], 16);
      part[n][j] += __shfl_xor(part[n][j], 32);
    }
  if (lane < 16) {
    #pragma unroll
    for (int n = 0; n < 4; ++n)
      #pragma unroll
      for (int j = 0; j < 6; ++j) red[w][n * 16 + l15][j] = part[n][j];
  }
  __syncthreads();
  if (t < 64) {
    int q = t >> 5;
    if (q < nvalid) {
      int node = (q ? g1 : g0) * 32 + (t & 31);
      #pragma unroll
      for (int j = 0; j < 6; ++j) {
        float sv = bn2[branch * 6 + j];
        #pragma unroll
        for (int ww = 0; ww < 8; ++ww) sv += red[ww][t][j];
        if (j < 3) n_head[(size_t)node * 3 + j] = sv;
        else       n_var[(size_t)node * 3 + (j - 3)] = sv * sv;
      }
    }
  }
}

// ---------- graph stage-1: hg = relu(xg @ Ws + bs), 64 graphs/block ----------
#define GT_MAX 80
__global__ __launch_bounds__(512, 4) void gstage1_kernel(
    const unsigned short* __restrict__ xg,
    const int* __restrict__ meta,
    const int* __restrict__ perm,
    const unsigned short* __restrict__ WsTf,
    const float* __restrict__ bs_,
    unsigned short* __restrict__ hg) {
  __shared__ __align__(16) unsigned short xtile[32768];
  __shared__ int gidl[64];

  int i = blockIdx.x, branch = -1, permOff = 0, nvalid = 0;
  for (int c = 0; c < N_CHUNKS; ++c) {
    int pb = 0;
    for (int b = 0; b < 4; ++b) {
      int cnt = meta[c * 4 + b];
      int gt = (cnt + 63) >> 6;
      if (branch < 0 && i < gt) { branch = b; permOff = c * CHUNK_G + pb + i * 64; nvalid = min(64, cnt - i * 64); }
      if (branch < 0) i -= gt;
      pb += cnt;
    }
  }
  if (branch < 0) return;

  const int t = threadIdx.x;
  const int lane = t & 63, w = t >> 6, l15 = lane & 15, l4 = lane >> 4;

  if (t < 64) gidl[t] = perm[permOff + min(t, nvalid - 1)];
  __syncthreads();

  for (int idx = t; idx < 4096; idx += 512) {
    int row = idx >> 6;
    int c8  = (idx & 63) * 8;
    u16x8 v = *(const u16x8*)&xg[(size_t)gidl[row] * HID + c8];
    int kk = c8 >> 5, ln = (c8 >> 3) & 3;
    *(u16x8*)&xtile[(((row >> 4) * 16 + kk) * 64 + ((row & 15) + ln * 16)) * 8] = v;
  }
  __syncthreads();

  f32x4 acc[4][4];
  #pragma unroll
  for (int m = 0; m < 4; ++m)
    #pragma unroll
    for (int n = 0; n < 4; ++n) acc[m][n] = (f32x4)0.f;

  const unsigned short* wbase = WsTf + ((size_t)(branch * 32 + w * 4)) * 8192 + lane * 8;
  const unsigned short* xbase = xtile + lane * 8;
  #pragma unroll
  for (int kk = 0; kk < 16; ++kk) {
    bf16x8 af[4];
    #pragma unroll
    for (int m = 0; m < 4; ++m)
      af[m] = *(const bf16x8*)(wbase + (m * 16 + kk) * 512);
    bf16x8 bfr[4];
    #pragma unroll
    for (int n = 0; n < 4; ++n)
      bfr[n] = *(const bf16x8*)(xbase + (n * 16 + kk) * 512);
    #pragma unroll
    for (int m = 0; m < 4; ++m)
      #pragma unroll
      for (int n = 0; n < 4; ++n)
        acc[m][n] = mfma_bf16(af[m], bfr[n], acc[m][n]);
  }

  const float* B1 = bs_ + branch * HID;
  #pragma unroll
  for (int m = 0; m < 4; ++m) {
    #pragma unroll
    for (int n = 0; n < 4; ++n) {
      int row = n * 16 + l15;
      if (row < nvalid) {
        int g = gidl[row];
        int hcb = w * 64 + m * 16 + l4 * 4;
        ushort4 hv;
        hv.x = f2bf(fmaxf(acc[m][n][0] + B1[hcb + 0], 0.f));
        hv.y = f2bf(fmaxf(acc[m][n][1] + B1[hcb + 1], 0.f));
        hv.z = f2bf(fmaxf(acc[m][n][2] + B1[hcb + 2], 0.f));
        hv.w = f2bf(fmaxf(acc[m][n][3] + B1[hcb + 3], 0.f));
        *(ushort4*)(hg + (size_t)g * HID + hcb) = hv;
      }
    }
  }
}

// ---------- graph stage-2: og = hg @ Wg[b] + bg, 16 graphs/block -------------
#define G2_MAX 272
__global__ __launch_bounds__(256) void gstage2_kernel(
    const int* __restrict__ meta,
    const int* __restrict__ perm,
    const unsigned short* __restrict__ hg,
    const unsigned short* __restrict__ WgT,
    const float* __restrict__ bg,
    float* __restrict__ g_head,
    float* __restrict__ g_var) {
  __shared__ int gidl[16];
  int i = blockIdx.x, branch = -1, permOff = 0, nvalid = 0;
  for (int c = 0; c < N_CHUNKS; ++c) {
    int pb = 0;
    for (int b = 0; b < 4; ++b) {
      int cnt = meta[c * 4 + b];
      int gt = (cnt + 15) >> 4;
      if (branch < 0 && i < gt) { branch = b; permOff = c * CHUNK_G + pb + i * 16; nvalid = min(16, cnt - i * 16); }
      if (branch < 0) i -= gt;
      pb += cnt;
    }
  }
  if (branch < 0) return;

  const int t = threadIdx.x;
  const int lane = t & 63, w = t >> 6, l15 = lane & 15, l4 = lane >> 4;

  if (t < 16) gidl[t] = perm[permOff + min(t, nvalid - 1)];
  __syncthreads();

  f32x4 acc2[2];
  acc2[0] = (f32x4)0.f; acc2[1] = (f32x4)0.f;
  const unsigned short* arow = hg + (size_t)gidl[l15] * HID + l4 * 8;
  const unsigned short* brow = WgT + ((size_t)branch * 128 + w * 32 + l15) * 512 + l4 * 8;
  #pragma unroll
  for (int ks = 0; ks < 16; ++ks) {
    bf16x8 a  = *(const bf16x8*)(arow + ks * 32);
    bf16x8 b0 = *(const bf16x8*)(brow + ks * 32);
    bf16x8 b1 = *(const bf16x8*)(brow + 16 * 512 + ks * 32);
    acc2[0] = mfma_bf16(a, b0, acc2[0]);
    acc2[1] = mfma_bf16(a, b1, acc2[1]);
  }
  #pragma unroll
  for (int n2 = 0; n2 < 2; ++n2) {
    int j = w * 32 + n2 * 16 + l15;
    if (j < 100) {
      float bias = bg[branch * 100 + j];
      #pragma unroll
      for (int rr = 0; rr < 4; ++rr) {
        int r = l4 * 4 + rr;
        if (r < nvalid) {
          int g = gidl[r];
          float val = acc2[n2][rr] + bias;
          if (j < 50) g_head[(size_t)g * 50 + j] = val;
          else        g_var[(size_t)g * 50 + (j - 50)] = val * val;
        }
      }
    }
  }
}

extern "C" void kernel_launch(void* const* d_in, const int* in_sizes, int n_in,
                              void* d_out, int out_size, void* d_ws, size_t ws_size,
                              hipStream_t stream) {
  const float* x    = (const float*)d_in[0];
  const float* Ws   = (const float*)d_in[1];
  const float* bs   = (const float*)d_in[2];
  const float* Wg   = (const float*)d_in[3];
  const float* bg   = (const float*)d_in[4];
  const float* Wn1  = (const float*)d_in[5];
  const float* bn1  = (const float*)d_in[6];
  const float* Wn2  = (const float*)d_in[7];
  const float* bn2  = (const float*)d_in[8];
  const int* dsid   = (const int*)d_in[10];

  float* out    = (float*)d_out;
  float* g_head = out;
  float* g_var  = out + (size_t)N_GRAPHS * 50;
  float* n_head = out + (size_t)2 * N_GRAPHS * 50;
  float* n_var  = n_head + (size_t)N_NODES * 3;

  char* ws = (char*)d_ws;
  int* perm = (int*)(ws);                                   // 16,384
  int* meta = (int*)(ws + 16384);                           // 256
  unsigned short* W1Tf = (unsigned short*)(ws + 16640);     // 2,097,152
  unsigned short* WsTf = (unsigned short*)(ws + 2113792);   // 2,097,152
  unsigned short* WgT  = (unsigned short*)(ws + 4210944);   // 524,288
  unsigned short* xg   = (unsigned short*)(ws + 4735232);   // 4,194,304
  unsigned short* hg   = (unsigned short*)(ws + 8929536);   // 4,194,304
  unsigned short* xb   = (unsigned short*)(ws + 13123840);  // 33,554,432
  if (ws_size < 46678272) return;

  bucket_kernel<<<dim3(1), dim3(512), 0, stream>>>(dsid, perm, meta);
  prep_wf_kernel<<<dim3(256), dim3(256), 0, stream>>>(Wn1, Ws, W1Tf, WsTf);
  prep_wg_kernel<<<dim3(1024), dim3(256), 0, stream>>>(Wg, WgT);
  for (int c = 0; c < N_CHUNKS; ++c) {
    convert_pool_kernel<<<dim3(CHUNK_G), dim3(512), 0, stream>>>(
        x, xb, xg, c * CHUNK_G);
    node_gemm_kernel<<<dim3(B_BLOCKS), dim3(512), 0, stream>>>(
        xb, meta + c * 4, perm + c * CHUNK_G, W1Tf, bn1, Wn2, bn2,
        n_head, n_var, c * CHUNK_G);
  }
  gstage1_kernel<<<dim3(GT_MAX), dim3(512), 0, stream>>>(
      xg, meta, perm, WsTf, bs, hg);
  gstage2_kernel<<<dim3(G2_MAX), dim3(256), 0, stream>>>(
      meta, perm, hg, WgT, bg, g_head, g_var);
}